// Round 8
// baseline (275.558 us; speedup 1.0000x reference)
//
#include <hip/hip_runtime.h>

#define NUM_REGIONS 32
#define NBINS 33                        // ws layout keeps 33 (bin 0 unused)
#define BATCH 4
#define DHW (160*192*192)               // 5,898,240 per volume
#define NVEC_PER_BATCH (DHW/4)          // 1,474,560 float4 vectors per batch
#define BLOCKS_PER_BATCH 512
#define NBLOCKS (BATCH*BLOCKS_PER_BATCH)                 // 2048
#define VEC_PER_BLOCK (NVEC_PER_BATCH/BLOCKS_PER_BATCH)  // 2880
#define ITERS 12                        // 11 full + tail (64 threads)
#define COL_STRIDE 129                  // hist bank = (bin+col)%32
#define RED_STRIDE 257                  // acc-spill bank = (bin+tid)%32
#define QSCALE 262144.0f                // 2^18 fixed point for DS path
#define INV_QSCALE (1.0f/262144.0f)
#define CNT_SHIFT 25
#define XS_MASK ((1u<<CNT_SHIFT)-1u)
#define EPS 1e-8f

// ---------------------------------------------------------------------------
// Kernel 1 (R7): HYBRID scatter — DS atomic unit and VALU are independent
// pipes (R5: DS ~2.1 cy/elem/CU; R6: VALU ~1.5 cy/elem/CU). Split the 4
// components: x,y -> register select chain (32 bins, packed V=xs+256*cnt);
// w -> LDS u32 atomic (packed fixed-point); z alternates DS/VALU by iter
// parity (avg 1.5 DS : 2.5 VALU). Both pipes run concurrently.
// Per-column hist count <= 36 < 128; per-lane-bin VALU count <= 30.
// ws layout: ws[0..132) = xs sums (float), ws[132..264) = counts (float).
// ---------------------------------------------------------------------------
__global__ __launch_bounds__(256, 4) void region_sums_kernel(
    const float* __restrict__ x,
    const int*   __restrict__ seg,
    float*       __restrict__ ws)
{
    __shared__ unsigned int hist[NBINS * COL_STRIDE];   // 17,028 B (reused as float red[16][257])
    __shared__ float part_h_xs [8][32];                 // hist partials
    __shared__ float part_h_cnt[8][32];
    __shared__ float partA_xs[16][16];                  // acc-pass partials
    __shared__ float partA_cnt[16][16];
    __shared__ float tot_xs[32];
    __shared__ float tot_cnt[32];

    float acc[32];
    #pragma unroll
    for (int b = 0; b < 32; ++b) acc[b] = 0.0f;

    const int tid = threadIdx.x;
    const int col = tid >> 1;

    for (int i = tid; i < NBINS * COL_STRIDE; i += 256) hist[i] = 0u;
    __syncthreads();

    const int batch = blockIdx.x >> 9;                  // 512 blocks per batch
    const int local = blockIdx.x & 511;
    const int vbase = batch * NVEC_PER_BATCH + local * VEC_PER_BLOCK;

    const float4* __restrict__ xv4 = (const float4*)x;
    const int4*   __restrict__ sv4 = (const int4*)seg;

    #define OFFK(k) ((((k)*256 + tid) < VEC_PER_BLOCK) ? ((k)*256 + tid) : (VEC_PER_BLOCK-1))

    // 3-deep rolling prefetch, named registers only
    float4 xA = xv4[vbase + OFFK(0)]; int4 sA = sv4[vbase + OFFK(0)];
    float4 xB = xv4[vbase + OFFK(1)]; int4 sB = sv4[vbase + OFFK(1)];
    float4 xC = xv4[vbase + OFFK(2)]; int4 sC = sv4[vbase + OFFK(2)];

    #pragma unroll 1
    for (int k = 0; k < ITERS; ++k) {
        const int kn = (k + 3 < ITERS) ? (k + 3) : (ITERS - 1);
        float4 xN = xv4[vbase + OFFK(kn)];
        int4   sN = sv4[vbase + OFFK(kn)];

        float p0 = __fdividef(1.0f, 1.0f + __expf(-xA.x));
        float p1 = __fdividef(1.0f, 1.0f + __expf(-xA.y));
        float p2 = __fdividef(1.0f, 1.0f + __expf(-xA.z));
        float p3 = __fdividef(1.0f, 1.0f + __expf(-xA.w));

        const bool active = (k * 256 + tid) < VEC_PER_BLOCK;  // k<11 always true
        if (active) {
            // DS pipe: comp w always
            unsigned qw = (unsigned)(fmaf(p3, QSCALE, 0.5f)) + (1u << CNT_SHIFT);
            atomicAdd(&hist[sA.w * COL_STRIDE + col], qw);

            float P0 = p0 + 256.0f;
            float P1 = p1 + 256.0f;

            if (k & 1) {
                // odd iter: z also to DS; VALU handles x,y
                unsigned qz = (unsigned)(fmaf(p2, QSCALE, 0.5f)) + (1u << CNT_SHIFT);
                atomicAdd(&hist[sA.z * COL_STRIDE + col], qz);
                #pragma unroll
                for (int b = 0; b < 32; ++b) {
                    acc[b] += (sA.x == b + 1) ? P0 : 0.0f;
                    acc[b] += (sA.y == b + 1) ? P1 : 0.0f;
                }
            } else {
                // even iter: VALU handles x,y,z
                float P2 = p2 + 256.0f;
                #pragma unroll
                for (int b = 0; b < 32; ++b) {
                    acc[b] += (sA.x == b + 1) ? P0 : 0.0f;
                    acc[b] += (sA.y == b + 1) ? P1 : 0.0f;
                    acc[b] += (sA.z == b + 1) ? P2 : 0.0f;
                }
            }
        }

        xA = xB; sA = sB; xB = xC; sB = sC; xC = xN; sC = sN;
    }
    #undef OFFK
    __syncthreads();

    // --- hist reduce: 8 groups x 32 bins, 16 cols each (conflict-free) ---
    {
        const int bin = (tid & 31) + 1;
        const int g   = tid >> 5;
        float xs = 0.0f, cnt = 0.0f;
        #pragma unroll
        for (int j = 0; j < 16; ++j) {
            unsigned V = hist[bin * COL_STRIDE + g * 16 + j];
            cnt += (float)(V >> CNT_SHIFT);
            xs  += (float)(V & XS_MASK);
        }
        part_h_xs [g][bin - 1] = xs * INV_QSCALE;
        part_h_cnt[g][bin - 1] = cnt;
    }
    __syncthreads();                     // hist reads done -> overlay as float

    float* redf = (float*)hist;          // 16*257*4 = 16,448 B <= 17,028 B

    // --- acc pass A: regions 1..16 ---
    #pragma unroll
    for (int b = 0; b < 16; ++b) redf[b * RED_STRIDE + tid] = acc[b];
    __syncthreads();
    {
        const int bin = tid & 15;        // 16 bins x 16 groups x 16 cols
        const int g   = tid >> 4;
        float xs = 0.0f, cnt = 0.0f;
        #pragma unroll
        for (int j = 0; j < 16; ++j) {
            float V = redf[bin * RED_STRIDE + g * 16 + j];
            float c = truncf(V * (1.0f / 256.0f));
            cnt += c;
            xs  += V - 256.0f * c;
        }
        partA_xs [g][bin] = xs;
        partA_cnt[g][bin] = cnt;
    }
    __syncthreads();
    if (tid < 16) {
        float xs = 0.0f, cnt = 0.0f;
        #pragma unroll
        for (int g = 0; g < 16; ++g) { xs += partA_xs[g][tid]; cnt += partA_cnt[g][tid]; }
        tot_xs[tid] = xs; tot_cnt[tid] = cnt;
    }
    // --- acc pass B: regions 17..32 (spill overlaps the fold above) ---
    #pragma unroll
    for (int b = 0; b < 16; ++b) redf[b * RED_STRIDE + tid] = acc[16 + b];
    __syncthreads();
    {
        const int bin = tid & 15;
        const int g   = tid >> 4;
        float xs = 0.0f, cnt = 0.0f;
        #pragma unroll
        for (int j = 0; j < 16; ++j) {
            float V = redf[bin * RED_STRIDE + g * 16 + j];
            float c = truncf(V * (1.0f / 256.0f));
            cnt += c;
            xs  += V - 256.0f * c;
        }
        partA_xs [g][bin] = xs;
        partA_cnt[g][bin] = cnt;
    }
    __syncthreads();
    if (tid < 16) {
        float xs = 0.0f, cnt = 0.0f;
        #pragma unroll
        for (int g = 0; g < 16; ++g) { xs += partA_xs[g][tid]; cnt += partA_cnt[g][tid]; }
        tot_xs[16 + tid] = xs; tot_cnt[16 + tid] = cnt;
    }
    __syncthreads();

    if (tid < 32) {
        float xs = tot_xs[tid], cnt = tot_cnt[tid];
        #pragma unroll
        for (int g = 0; g < 8; ++g) { xs += part_h_xs[g][tid]; cnt += part_h_cnt[g][tid]; }
        atomicAdd(&ws[batch * NBINS + tid + 1], xs);
        atomicAdd(&ws[BATCH * NBINS + batch * NBINS + tid + 1], cnt);
    }
}

// ---------------------------------------------------------------------------
// Kernel 2: dice + mean epilogue. One wave; lane r handles region r (1..32).
// ---------------------------------------------------------------------------
__global__ void region_dice_final_kernel(
    const float* __restrict__ ws,
    float*       __restrict__ out)
{
    const int lane = threadIdx.x;   // 0..63
    float loss_sum = 0.0f;

    for (int b = 0; b < BATCH; ++b) {
        bool  valid = false;
        float dice  = 0.0f;
        if (lane >= 1 && lane <= NUM_REGIONS) {
            float xs  = ws[b * NBINS + lane];
            float cnt = ws[BATCH * NBINS + b * NBINS + lane];
            valid = (cnt > 0.0f);
            if (valid) dice = 2.0f * xs / (xs + cnt + EPS);
        }
        unsigned long long m = __ballot(valid);
        int n_valid = __popcll(m);

        float s = dice;
        #pragma unroll
        for (int off = 32; off >= 1; off >>= 1) s += __shfl_down(s, off);

        float mean_dice = s / (float)((n_valid > 1) ? n_valid : 1);
        float loss_b    = (n_valid > 0) ? (1.0f - mean_dice) : 1.0f;
        loss_sum += loss_b;
    }

    if (lane == 0) out[0] = loss_sum * (1.0f / BATCH);
}

extern "C" void kernel_launch(void* const* d_in, const int* in_sizes, int n_in,
                              void* d_out, int out_size, void* d_ws, size_t ws_size,
                              hipStream_t stream)
{
    const float* x   = (const float*)d_in[0];
    const int*   seg = (const int*)d_in[1];
    float*       ws  = (float*)d_ws;

    // d_ws is poisoned with 0xAA before every timed launch — zero the bins.
    hipMemsetAsync(d_ws, 0, 2 * BATCH * NBINS * sizeof(float), stream);

    region_sums_kernel<<<NBLOCKS, 256, 0, stream>>>(x, seg, ws);
    region_dice_final_kernel<<<1, 64, 0, stream>>>(ws, (float*)d_out);
}

// Round 9
// 221.989 us; speedup vs baseline: 1.2413x; 1.2413x over previous
//
#include <hip/hip_runtime.h>

#define NUM_REGIONS 32
#define NBINS 33                        // ws layout keeps 33 (bin 0 unused)
#define BATCH 4
#define DHW (160*192*192)               // 5,898,240 per volume
#define NVEC_PER_BATCH (DHW/4)          // 1,474,560 float4 vectors per batch
#define BLOCKS_PER_BATCH 256
#define NBLOCKS (BATCH*BLOCKS_PER_BATCH)                 // 1024 = 4 per CU resident
#define VEC_PER_BLOCK (NVEC_PER_BATCH/BLOCKS_PER_BATCH)  // 5760
#define ITERS 23                        // 22 full + tail (128 threads)
#define HCOLS 256                       // hist cols = tid -> bank = tid%32 (2-way, free)
#define RED_STRIDE 257                  // acc-spill bank = (bin+tid)%32
#define QSCALE 262144.0f                // 2^18 fixed point for DS path
#define INV_QSCALE (1.0f/262144.0f)
#define CNT_SHIFT 25
#define XS_MASK ((1u<<CNT_SHIFT)-1u)
#define EPS 1e-8f

// ---------------------------------------------------------------------------
// Kernel 1 (R9): HYBRID scatter, spill-free. R8's regression was register
// spill (WRITE_SIZE 207 MB of scratch), not a wrong pipe theory. Fixed 2:2
// split, single code path:
//   comps x,y -> VALU register select chain (32 bins, packed V = xs+256*cnt)
//   comps z,w -> LDS ds_add_u32, DETERMINISTIC banks: hist[s*256+tid],
//                bank = tid%32 -> exactly 2-way (free). Isolates whether the
//                DS atomic unit's ~2.1 cy/lane is intrinsic or conflicts.
// Per-column DS count <= 46 < 128 (fits bits 25..31); xs <= 46*2^18 < 2^25.
// Per-lane-bin VALU count <= 46 -> V <= 46+256*46 = 11.8K, f32-exact cnt.
// ws layout: ws[0..132) = xs sums (float), ws[132..264) = counts (float).
// ---------------------------------------------------------------------------
__global__ __launch_bounds__(256) void region_sums_kernel(
    const float* __restrict__ x,
    const int*   __restrict__ seg,
    float*       __restrict__ ws)
{
    __shared__ unsigned int hist[NBINS * HCOLS];        // 33,792 B
    __shared__ float part_xs [8][32];                   //  1,024 B
    __shared__ float part_cnt[8][32];                   //  1,024 B

    float acc[32];
    #pragma unroll
    for (int b = 0; b < 32; ++b) acc[b] = 0.0f;

    const int tid = threadIdx.x;

    for (int i = tid; i < NBINS * HCOLS; i += 256) hist[i] = 0u;
    __syncthreads();

    const int batch = blockIdx.x >> 8;                  // 256 blocks per batch
    const int local = blockIdx.x & 255;
    const int vbase = batch * NVEC_PER_BATCH + local * VEC_PER_BLOCK;

    const float4* __restrict__ xv4 = (const float4*)x;
    const int4*   __restrict__ sv4 = (const int4*)seg;

    #define OFFK(k) ((((k)*256 + tid) < VEC_PER_BLOCK) ? ((k)*256 + tid) : (VEC_PER_BLOCK-1))

    // 2-deep rolling prefetch, named registers only (spill-safe)
    float4 xA = xv4[vbase + OFFK(0)]; int4 sA = sv4[vbase + OFFK(0)];
    float4 xB = xv4[vbase + OFFK(1)]; int4 sB = sv4[vbase + OFFK(1)];

    #pragma unroll 1
    for (int k = 0; k < ITERS; ++k) {
        const int kn = (k + 2 < ITERS) ? (k + 2) : (ITERS - 1);
        float4 xN = xv4[vbase + OFFK(kn)];
        int4   sN = sv4[vbase + OFFK(kn)];

        // sigmoid via exp + rcp (v_exp + v_rcp + adds; memory-error budget ok)
        float e0 = __expf(-xA.x);
        float e1 = __expf(-xA.y);
        float e2 = __expf(-xA.z);
        float e3 = __expf(-xA.w);
        float p0 = __builtin_amdgcn_rcpf(1.0f + e0);
        float p1 = __builtin_amdgcn_rcpf(1.0f + e1);
        float p2 = __builtin_amdgcn_rcpf(1.0f + e2);
        float p3 = __builtin_amdgcn_rcpf(1.0f + e3);

        const bool active = (k * 256 + tid) < VEC_PER_BLOCK;   // k<22 always
        if (active) {
            // --- DS pipe: comps z,w (deterministic bank = tid%32) ---
            unsigned qz = (unsigned)(fmaf(p2, QSCALE, 0.5f)) + (1u << CNT_SHIFT);
            unsigned qw = (unsigned)(fmaf(p3, QSCALE, 0.5f)) + (1u << CNT_SHIFT);
            atomicAdd(&hist[sA.z * HCOLS + tid], qz);
            atomicAdd(&hist[sA.w * HCOLS + tid], qw);

            // --- VALU pipe: comps x,y (32-bin select chain) ---
            float P0 = p0 + 256.0f;
            float P1 = p1 + 256.0f;
            #pragma unroll
            for (int b = 0; b < 32; ++b) {
                acc[b] += (sA.x == b + 1) ? P0 : 0.0f;
                acc[b] += (sA.y == b + 1) ? P1 : 0.0f;
            }
        }

        xA = xB; sA = sB; xB = xN; sB = sN;
    }
    #undef OFFK
    __syncthreads();

    // --- hist reduce: thread (g,bin) sums 32 cols, rotated by bin so the
    // 32 lanes of each half-wave hit 32 distinct banks (conflict-free) ---
    float h_xs, h_cnt;
    {
        const int bin = (tid & 31) + 1;
        const int g   = tid >> 5;
        float xs = 0.0f, cnt = 0.0f;
        #pragma unroll
        for (int j = 0; j < 32; ++j) {
            const int col = g * 32 + ((j + bin) & 31);
            unsigned V = hist[bin * HCOLS + col];
            cnt += (float)(V >> CNT_SHIFT);
            xs  += (float)(V & XS_MASK);
        }
        h_xs  = xs * INV_QSCALE;
        h_cnt = cnt;
    }
    __syncthreads();                     // hist reads done -> overlay as float

    float* redf = (float*)hist;          // 32*257*4 = 32,896 B <= 33,792 B

    // --- acc spill + reduce: red[bin][tid], bank (bin+tid)%32 (2-way free) ---
    #pragma unroll
    for (int b = 0; b < 32; ++b) redf[b * RED_STRIDE + tid] = acc[b];
    __syncthreads();
    {
        const int bin = tid & 31;
        const int g   = tid >> 5;
        float xs = 0.0f, cnt = 0.0f;
        #pragma unroll
        for (int j = 0; j < 32; ++j) {
            float V = redf[bin * RED_STRIDE + g * 32 + j];
            float c = truncf(V * (1.0f / 256.0f));
            cnt += c;
            xs  += V - 256.0f * c;
        }
        part_xs [g][bin] = xs;
        part_cnt[g][bin] = cnt;
    }
    __syncthreads();

    if (tid < 32) {
        float xs = 0.0f, cnt = 0.0f;
        #pragma unroll
        for (int g = 0; g < 8; ++g) {
            xs  += part_xs [g][tid];
            cnt += part_cnt[g][tid];
        }
        // add this thread's own hist partial? No — hist partials live in
        // (h_xs,h_cnt) of ALL 256 threads; fold them via part arrays reuse.
        atomicAdd(&ws[batch * NBINS + tid + 1], xs);
        atomicAdd(&ws[BATCH * NBINS + batch * NBINS + tid + 1], cnt);
    }
    __syncthreads();

    // --- fold hist partials (8 groups x 32 bins) through part arrays ---
    {
        const int bin = tid & 31;
        const int g   = tid >> 5;
        part_xs [g][bin] = h_xs;
        part_cnt[g][bin] = h_cnt;
    }
    __syncthreads();
    if (tid < 32) {
        float xs = 0.0f, cnt = 0.0f;
        #pragma unroll
        for (int g = 0; g < 8; ++g) {
            xs  += part_xs [g][tid];
            cnt += part_cnt[g][tid];
        }
        atomicAdd(&ws[batch * NBINS + tid + 1], xs);
        atomicAdd(&ws[BATCH * NBINS + batch * NBINS + tid + 1], cnt);
    }
}

// ---------------------------------------------------------------------------
// Kernel 2: dice + mean epilogue. One wave; lane r handles region r (1..32).
// ---------------------------------------------------------------------------
__global__ void region_dice_final_kernel(
    const float* __restrict__ ws,
    float*       __restrict__ out)
{
    const int lane = threadIdx.x;   // 0..63
    float loss_sum = 0.0f;

    for (int b = 0; b < BATCH; ++b) {
        bool  valid = false;
        float dice  = 0.0f;
        if (lane >= 1 && lane <= NUM_REGIONS) {
            float xs  = ws[b * NBINS + lane];
            float cnt = ws[BATCH * NBINS + b * NBINS + lane];
            valid = (cnt > 0.0f);
            if (valid) dice = 2.0f * xs / (xs + cnt + EPS);
        }
        unsigned long long m = __ballot(valid);
        int n_valid = __popcll(m);

        float s = dice;
        #pragma unroll
        for (int off = 32; off >= 1; off >>= 1) s += __shfl_down(s, off);

        float mean_dice = s / (float)((n_valid > 1) ? n_valid : 1);
        float loss_b    = (n_valid > 0) ? (1.0f - mean_dice) : 1.0f;
        loss_sum += loss_b;
    }

    if (lane == 0) out[0] = loss_sum * (1.0f / BATCH);
}

extern "C" void kernel_launch(void* const* d_in, const int* in_sizes, int n_in,
                              void* d_out, int out_size, void* d_ws, size_t ws_size,
                              hipStream_t stream)
{
    const float* x   = (const float*)d_in[0];
    const int*   seg = (const int*)d_in[1];
    float*       ws  = (float*)d_ws;

    // d_ws is poisoned with 0xAA before every timed launch — zero the bins.
    hipMemsetAsync(d_ws, 0, 2 * BATCH * NBINS * sizeof(float), stream);

    region_sums_kernel<<<NBLOCKS, 256, 0, stream>>>(x, seg, ws);
    region_dice_final_kernel<<<1, 64, 0, stream>>>(ws, (float*)d_out);
}

// Round 10
// 220.770 us; speedup vs baseline: 1.2482x; 1.0055x over previous
//
#include <hip/hip_runtime.h>

#define NUM_REGIONS 32
#define NBINS 33                        // ws layout keeps 33 (bin 0 unused)
#define BATCH 4
#define DHW (160*192*192)               // 5,898,240 per volume
#define NVEC_PER_BATCH (DHW/4)          // 1,474,560 float4 vectors per batch
#define BLOCKS_PER_BATCH 256
#define NBLOCKS (BATCH*BLOCKS_PER_BATCH)                 // 1024 = 4 per CU
#define VEC_PER_BLOCK (NVEC_PER_BATCH/BLOCKS_PER_BATCH)  // 5760
#define VALU_VECS 3200                  // waves 0-1: 25 per lane (128 lanes)
#define ITERS_V 25
#define DS_VECS 2560                    // waves 2-3: 20 per lane
#define ITERS_D 20
#define HCOLS 128                       // hist col = tid&127 -> bank 2-way (free)
#define RED_STRIDE 129                  // acc-spill bank = (bin+tid)%32
#define QSCALE 262144.0f                // 2^18 fixed point for DS path
#define INV_QSCALE (1.0f/262144.0f)
#define CNT_SHIFT 25
#define XS_MASK ((1u<<CNT_SHIFT)-1u)
#define EPS 1e-8f

// ---------------------------------------------------------------------------
// Kernel 1 (R10): WAVE-SPECIALIZED hybrid. R9 showed within-wave DS+VALU
// interleave fully serializes (sum, not max: a wave issuing a scattered
// ds_add appears held for the per-lane-serial processing ~134 cy). So split
// by WAVE: waves 0-1 = pure VALU select-chain scatter (no LDS in loop);
// waves 2-3 = pure fire-and-forget ds_add_u32 histogram. Separate waves
// co-schedule on a CU (m114 analog). Exact element split 3200/2560, no tails.
//   VALU acc: packed V = xs + 256*cnt per (lane,bin); <=100 elems -> exact.
//   DS hist:  packed u32 = round(p*2^18) + (1<<25); <=80 per (bin,col).
// ws layout: ws[0..132) = xs sums (float), ws[132..264) = counts (float).
// ---------------------------------------------------------------------------
__global__ __launch_bounds__(256) void region_sums_kernel(
    const float* __restrict__ x,
    const int*   __restrict__ seg,
    float*       __restrict__ ws)
{
    __shared__ unsigned int hist[NBINS * HCOLS];        // 16,896 B
    __shared__ float part_xs [8][32];                   //  1,024 B
    __shared__ float part_cnt[8][32];                   //  1,024 B

    const int tid = threadIdx.x;

    for (int i = tid; i < NBINS * HCOLS; i += 256) hist[i] = 0u;
    __syncthreads();

    const int batch = blockIdx.x >> 8;                  // 256 blocks per batch
    const int local = blockIdx.x & 255;
    const int vbase = batch * NVEC_PER_BATCH + local * VEC_PER_BLOCK;

    const float4* __restrict__ xv4 = (const float4*)x;
    const int4*   __restrict__ sv4 = (const int4*)seg;

    float acc[32];
    #pragma unroll
    for (int b = 0; b < 32; ++b) acc[b] = 0.0f;

    if (tid < 128) {
        // =========== VALU waves (0,1): pure register select chain ==========
        const int base = vbase + tid;                   // vectors 0..3199
        float4 xA = xv4[base];       int4 sA = sv4[base];
        float4 xB = xv4[base + 128]; int4 sB = sv4[base + 128];

        #pragma unroll 1
        for (int k = 0; k < ITERS_V; ++k) {
            const int kn = (k + 2 < ITERS_V) ? (k + 2) : (ITERS_V - 1);
            float4 xN = xv4[base + kn * 128];
            int4   sN = sv4[base + kn * 128];

            float P0 = __builtin_amdgcn_rcpf(1.0f + __expf(-xA.x)) + 256.0f;
            float P1 = __builtin_amdgcn_rcpf(1.0f + __expf(-xA.y)) + 256.0f;
            float P2 = __builtin_amdgcn_rcpf(1.0f + __expf(-xA.z)) + 256.0f;
            float P3 = __builtin_amdgcn_rcpf(1.0f + __expf(-xA.w)) + 256.0f;

            #pragma unroll
            for (int b = 0; b < 32; ++b) {
                acc[b] += (sA.x == b + 1) ? P0 : 0.0f;
                acc[b] += (sA.y == b + 1) ? P1 : 0.0f;
                acc[b] += (sA.z == b + 1) ? P2 : 0.0f;
                acc[b] += (sA.w == b + 1) ? P3 : 0.0f;
            }

            xA = xB; sA = sB; xB = xN; sB = sN;
        }
    } else {
        // =========== DS waves (2,3): pure LDS integer atomics ===============
        const int lane2 = tid - 128;                    // 0..127
        const int base  = vbase + VALU_VECS + lane2;    // vectors 3200..5759
        float4 xA = xv4[base];       int4 sA = sv4[base];
        float4 xB = xv4[base + 128]; int4 sB = sv4[base + 128];

        #pragma unroll 1
        for (int k = 0; k < ITERS_D; ++k) {
            const int kn = (k + 2 < ITERS_D) ? (k + 2) : (ITERS_D - 1);
            float4 xN = xv4[base + kn * 128];
            int4   sN = sv4[base + kn * 128];

            float p0 = __builtin_amdgcn_rcpf(1.0f + __expf(-xA.x));
            float p1 = __builtin_amdgcn_rcpf(1.0f + __expf(-xA.y));
            float p2 = __builtin_amdgcn_rcpf(1.0f + __expf(-xA.z));
            float p3 = __builtin_amdgcn_rcpf(1.0f + __expf(-xA.w));

            unsigned q0 = (unsigned)(fmaf(p0, QSCALE, 0.5f)) + (1u << CNT_SHIFT);
            unsigned q1 = (unsigned)(fmaf(p1, QSCALE, 0.5f)) + (1u << CNT_SHIFT);
            unsigned q2 = (unsigned)(fmaf(p2, QSCALE, 0.5f)) + (1u << CNT_SHIFT);
            unsigned q3 = (unsigned)(fmaf(p3, QSCALE, 0.5f)) + (1u << CNT_SHIFT);

            atomicAdd(&hist[sA.x * HCOLS + lane2], q0);
            atomicAdd(&hist[sA.y * HCOLS + lane2], q1);
            atomicAdd(&hist[sA.z * HCOLS + lane2], q2);
            atomicAdd(&hist[sA.w * HCOLS + lane2], q3);

            xA = xB; sA = sB; xB = xN; sB = sN;
        }
    }
    __syncthreads();

    // --- hist reduce: thread (g,bin) sums 16 cols, rotated for banks ---
    {
        const int bin = (tid & 31) + 1;
        const int g   = tid >> 5;
        float xs = 0.0f, cnt = 0.0f;
        #pragma unroll
        for (int j = 0; j < 16; ++j) {
            const int col = g * 16 + ((j + bin) & 15);
            unsigned V = hist[bin * HCOLS + col];
            cnt += (float)(V >> CNT_SHIFT);
            xs  += (float)(V & XS_MASK);
        }
        part_xs [g][bin - 1] = xs * INV_QSCALE;
        part_cnt[g][bin - 1] = cnt;
    }
    __syncthreads();

    // tid<32: fold hist partials into registers (part arrays reused below)
    float hxs = 0.0f, hcnt = 0.0f;
    if (tid < 32) {
        #pragma unroll
        for (int g = 0; g < 8; ++g) { hxs += part_xs[g][tid]; hcnt += part_cnt[g][tid]; }
    }
    // VALU-wave acc spill (overlays hist; its reads completed above)
    float* redf = (float*)hist;          // 32*129*4 = 16,512 B <= 16,896 B
    if (tid < 128) {
        #pragma unroll
        for (int b = 0; b < 32; ++b) redf[b * RED_STRIDE + tid] = acc[b];
    }
    __syncthreads();

    // --- acc reduce: thread (g,bin) sums 16 of the 128 VALU columns ---
    {
        const int bin = tid & 31;
        const int g   = tid >> 5;
        float xs = 0.0f, cnt = 0.0f;
        #pragma unroll
        for (int j = 0; j < 16; ++j) {
            const int col = g * 16 + ((j + bin) & 15);
            float V = redf[bin * RED_STRIDE + col];
            float c = truncf(V * (1.0f / 256.0f));
            cnt += c;
            xs  += V - 256.0f * c;
        }
        part_xs [g][bin] = xs;
        part_cnt[g][bin] = cnt;
    }
    __syncthreads();

    if (tid < 32) {
        float xs = hxs, cnt = hcnt;
        #pragma unroll
        for (int g = 0; g < 8; ++g) { xs += part_xs[g][tid]; cnt += part_cnt[g][tid]; }
        atomicAdd(&ws[batch * NBINS + tid + 1], xs);
        atomicAdd(&ws[BATCH * NBINS + batch * NBINS + tid + 1], cnt);
    }
}

// ---------------------------------------------------------------------------
// Kernel 2: dice + mean epilogue. One wave; lane r handles region r (1..32).
// ---------------------------------------------------------------------------
__global__ void region_dice_final_kernel(
    const float* __restrict__ ws,
    float*       __restrict__ out)
{
    const int lane = threadIdx.x;   // 0..63
    float loss_sum = 0.0f;

    for (int b = 0; b < BATCH; ++b) {
        bool  valid = false;
        float dice  = 0.0f;
        if (lane >= 1 && lane <= NUM_REGIONS) {
            float xs  = ws[b * NBINS + lane];
            float cnt = ws[BATCH * NBINS + b * NBINS + lane];
            valid = (cnt > 0.0f);
            if (valid) dice = 2.0f * xs / (xs + cnt + EPS);
        }
        unsigned long long m = __ballot(valid);
        int n_valid = __popcll(m);

        float s = dice;
        #pragma unroll
        for (int off = 32; off >= 1; off >>= 1) s += __shfl_down(s, off);

        float mean_dice = s / (float)((n_valid > 1) ? n_valid : 1);
        float loss_b    = (n_valid > 0) ? (1.0f - mean_dice) : 1.0f;
        loss_sum += loss_b;
    }

    if (lane == 0) out[0] = loss_sum * (1.0f / BATCH);
}

extern "C" void kernel_launch(void* const* d_in, const int* in_sizes, int n_in,
                              void* d_out, int out_size, void* d_ws, size_t ws_size,
                              hipStream_t stream)
{
    const float* x   = (const float*)d_in[0];
    const int*   seg = (const int*)d_in[1];
    float*       ws  = (float*)d_ws;

    // d_ws is poisoned with 0xAA before every timed launch — zero the bins.
    hipMemsetAsync(d_ws, 0, 2 * BATCH * NBINS * sizeof(float), stream);

    region_sums_kernel<<<NBLOCKS, 256, 0, stream>>>(x, seg, ws);
    region_dice_final_kernel<<<1, 64, 0, stream>>>(ws, (float*)d_out);
}